// Round 1
// baseline (852.103 us; speedup 1.0000x reference)
//
#include <hip/hip_runtime.h>
#include <stdint.h>

typedef short bf8 __attribute__((ext_vector_type(8)));   // 8 bf16 (4 VGPRs)
typedef float f4  __attribute__((ext_vector_type(4)));   // MFMA acc
typedef unsigned short u16;
typedef unsigned long long u64;

#define LOG2E 1.4426950408889634f

__device__ __forceinline__ u16 f2bf(float f){
  uint32_t u = __builtin_bit_cast(uint32_t, f);
  u += 0x7fffu + ((u >> 16) & 1u);
  return (u16)(u >> 16);
}
// sigmoid of value pre-scaled by log2e: 1/(1+2^-a)
__device__ __forceinline__ float sigm_ps(float a){
  return __builtin_amdgcn_rcpf(1.0f + __builtin_amdgcn_exp2f(-a));
}

// ---------------------------------------------------------------------------
// Prep: prescaled bf16 weights W0c[512][160]=[Whh0|Wih0|0], W1c[512][256]=
// [Whh1|Wih1]; rows scaled log2e (i,f,o) / 2*log2e (g); prescaled biases;
// zero the progress counters (ws is poisoned 0xAA before every launch!).
// ---------------------------------------------------------------------------
__global__ void prep_kernel(const float* __restrict__ Wih0, const float* __restrict__ Whh0,
                            const float* __restrict__ bih0, const float* __restrict__ bhh0,
                            const float* __restrict__ Wih1, const float* __restrict__ Whh1,
                            const float* __restrict__ bih1, const float* __restrict__ bhh1,
                            u16* __restrict__ W0c, u16* __restrict__ W1c,
                            float* __restrict__ bias0, float* __restrict__ bias1,
                            int* __restrict__ prog){
  int g = blockIdx.x;      // gate row 0..511
  int t = threadIdx.x;     // 0..63
  float s = (g >= 256 && g < 384) ? 2.0f * LOG2E : LOG2E;
  for(int k = t; k < 160; k += 64){
    float v = 0.0f;
    if(k < 128)      v = Whh0[g*128 + k];
    else if(k < 146) v = Wih0[g*18 + (k-128)];
    W0c[g*160 + k] = f2bf(v * s);
  }
  for(int k = t; k < 256; k += 64){
    float v = (k < 128) ? Whh1[g*128 + k] : Wih1[g*128 + (k-128)];
    W1c[g*256 + k] = f2bf(v * s);
  }
  if(t == 0){
    bias0[g] = (bih0[g] + bhh0[g]) * s;
    bias1[g] = (bih1[g] + bhh1[g]) * s;
  }
  if(g == 0 && t < 32) prog[t] = 0;
}

// ---------------------------------------------------------------------------
// Fused 2-layer LSTM, gate-major MFMA, producer/consumer overlap.
// 64 blocks x 512 threads. bid<32: L0-role (rows rb*16..+16), else L1-role.
//
// Handoff redesign vs previous version (numerics identical):
//  * L0: lgkm-only barrier + s_waitcnt vmcnt(1) (in-order vmcnt retirement =>
//    all waves' step-(t-1) h1 stores complete at barrier exit), then tid0
//    publishes prog=t with a RELAXED store (no per-step vmcnt(0) drain).
//  * L1: 4-slot LDS h1 ring, 3-steps-ahead prefetch; polls prog only when the
//    cached 'seen' is insufficient. Poll latency + load latency leave the
//    per-step critical path entirely in steady state. lgkm-only barriers.
// ---------------------------------------------------------------------------
__global__ __launch_bounds__(512, 2)
void lstm_fused(const u16* __restrict__ Wc0, const u16* __restrict__ Wc1,
                const float* __restrict__ bias0, const float* __restrict__ bias1,
                const float* __restrict__ xin,   // (512,512,18) f32
                u64* __restrict__ h1g,           // [T][512 rows][32 u64] bf16x4
                int* __restrict__ prog,          // [32] per-rowblock progress
                const float* __restrict__ Wfc1, const float* __restrict__ bfc1,
                const float* __restrict__ Wfc2, const float* __restrict__ bfc2,
                float* __restrict__ out)         // (512,) f32
{
  // L0 state: [h1(128) | x(18) | zero-pad] per row; row stride 168 u16 = 336B
  // (16B-aligned, 84 dw -> lane stride 20 banks: 2-way, free).
  __shared__ __align__(16) u16  hb[2][16][168];
  // L1 h2 state; 136 u16 = 272B rows (16B-aligned, 68 dw -> 2-way).
  __shared__ __align__(16) u16  h2b[2][16][136];
  // L1 h1 prefetch ring (slot = t&3).
  __shared__ __align__(16) u16  ring[4][16][136];
  __shared__ __align__(16) float ffin[16][132];  // final h2 f32 for FC head

  const int tid  = threadIdx.x;
  const int wave = tid >> 6;
  const int lane = tid & 63;
  const int quad = lane >> 4;
  const int l15  = lane & 15;
  const bool isL0 = (blockIdx.x < 32);
  const int rb   = isL0 ? blockIdx.x : (blockIdx.x - 32);
  const int rowbase = rb * 16;

  if(isL0){
    // ---------------- L0 role: K=160 = [h0(128) | x(18) | 0(14)], KT=5 ----
    bf8 A[4][5];
#pragma unroll
    for(int q = 0; q < 4; q++){
      const u16* wp = Wc0 + (u64)(128*q + 16*wave + l15)*160 + quad*8;
#pragma unroll
      for(int kt = 0; kt < 5; kt++) A[q][kt] = *(const bf8*)(wp + kt*32);
    }
    f4 bini[4];
#pragma unroll
    for(int q = 0; q < 4; q++) bini[q] = *(const f4*)(bias0 + 128*q + 16*wave + quad*4);
    float c[4] = {0.f,0.f,0.f,0.f};

    // zero state (zeros double as h=0 init and K-padding)
    for(int i = tid; i < 2*16*168; i += 512) ((u16*)hb)[i] = 0;
    __syncthreads();
    // stage x(0)
    if(tid < 288){
      int r = tid/18, k = tid - 18*r;
      hb[0][r][128+k] = f2bf(xin[((u64)(rowbase+r)*512 + 0)*18 + k]);
    }
    __syncthreads();

    int sr = 0, sk = 0;
    if(tid < 288){ sr = tid/18; sk = tid - 18*sr; }

    for(int t = 0; t < 512; t++){
      const int cur = t & 1, nxt = cur ^ 1;
      // prefetch x(t+1) (issued first => oldest vmem this step)
      float xv = 0.f;
      if(tid < 288 && t < 511)
        xv = xin[((u64)(rowbase+sr)*512 + (t+1))*18 + sk];

      bf8 B[5];
      const u16* br = &hb[cur][l15][quad*8];
#pragma unroll
      for(int kt = 0; kt < 5; kt++) B[kt] = *(const bf8*)(br + kt*32);

      f4 acc[4];
#pragma unroll
      for(int q = 0; q < 4; q++) acc[q] = bini[q];
#pragma unroll
      for(int kt = 0; kt < 5; kt++){
#pragma unroll
        for(int q = 0; q < 4; q++)
          acc[q] = __builtin_amdgcn_mfma_f32_16x16x32_bf16(A[q][kt], B[kt], acc[q], 0,0,0);
      }

      // in-register update: comps j=16w+quad*4+r, row l15
      u64 hpack; u16* hp = (u16*)&hpack;
#pragma unroll
      for(int r = 0; r < 4; r++){
        float ig = sigm_ps(acc[0][r]);
        float fg = sigm_ps(acc[1][r]);
        float gg = 2.f*sigm_ps(acc[2][r]) - 1.f;
        float og = sigm_ps(acc[3][r]);
        c[r] = fg*c[r] + ig*gg;
        float th = 2.f*sigm_ps(c[r]*(2.f*LOG2E)) - 1.f;
        hp[r] = f2bf(og*th);
      }
      *(u64*)(&hb[nxt][l15][16*wave + quad*4]) = hpack;
      // publish h1(t) device-visible (relaxed; completion enforced by vmcnt)
      __hip_atomic_store(h1g + ((u64)t*512 + rowbase + l15)*32 + 4*wave + quad,
                         hpack, __ATOMIC_RELAXED, __HIP_MEMORY_SCOPE_AGENT);
      if(tid < 288 && t < 511) hb[nxt][sr][128+sk] = f2bf(xv);

      // lgkm-only barrier + vmcnt(1): allows THIS step's h1 store to stay in
      // flight, forces step-(t-1) stores (per wave, in-order) to be complete.
      __builtin_amdgcn_sched_barrier(0);
      asm volatile("s_waitcnt vmcnt(1) lgkmcnt(0)" ::: "memory");
      __builtin_amdgcn_s_barrier();
      __builtin_amdgcn_sched_barrier(0);
      // h1(0..t-1) globally complete => publish prog=t, relaxed (no drain).
      if(tid == 0)
        __hip_atomic_store(prog + rb, t, __ATOMIC_RELAXED, __HIP_MEMORY_SCOPE_AGENT);
    }
    // tail: drain everything, then publish 512
    asm volatile("s_waitcnt vmcnt(0)" ::: "memory");
    __builtin_amdgcn_s_barrier();
    if(tid == 0)
      __hip_atomic_store(prog + rb, 512, __ATOMIC_RELAXED, __HIP_MEMORY_SCOPE_AGENT);
  } else {
    // ---------------- L1 role: K=256 = [h2(128) | h1(128)], KT=8 ----------
    bf8 A[4][8];
#pragma unroll
    for(int q = 0; q < 4; q++){
      const u16* wp = Wc1 + (u64)(128*q + 16*wave + l15)*256 + quad*8;
#pragma unroll
      for(int kt = 0; kt < 8; kt++) A[q][kt] = *(const bf8*)(wp + kt*32);
    }
    f4 bini[4];
#pragma unroll
    for(int q = 0; q < 4; q++) bini[q] = *(const f4*)(bias1 + 128*q + 16*wave + quad*4);
    float c[4] = {0.f,0.f,0.f,0.f};

    for(int i = tid; i < 2*16*136; i += 512) ((u16*)h2b)[i] = 0;

    const int pr = tid >> 5;          // staging row 0..15
    const int pu = tid & 31;          // staging u64-chunk (4 comps)
    int seen = 0;
    __syncthreads();

    // prologue: stage h1(0)->ring0, h1(1)->ring1, preload pv=h1(2)
    while(seen < 2){
      seen = __hip_atomic_load(prog + rb, __ATOMIC_ACQUIRE, __HIP_MEMORY_SCOPE_AGENT);
      if(seen < 2) __builtin_amdgcn_s_sleep(2);
    }
    {
      u64 v0 = __hip_atomic_load(h1g + ((u64)0*512 + rowbase + pr)*32 + pu,
                                 __ATOMIC_RELAXED, __HIP_MEMORY_SCOPE_AGENT);
      *(u64*)(&ring[0][pr][pu*4]) = v0;
      u64 v1 = __hip_atomic_load(h1g + ((u64)1*512 + rowbase + pr)*32 + pu,
                                 __ATOMIC_RELAXED, __HIP_MEMORY_SCOPE_AGENT);
      *(u64*)(&ring[1][pr][pu*4]) = v1;
    }
    while(seen < 3){
      seen = __hip_atomic_load(prog + rb, __ATOMIC_ACQUIRE, __HIP_MEMORY_SCOPE_AGENT);
      if(seen < 3) __builtin_amdgcn_s_sleep(2);
    }
    u64 pv = __hip_atomic_load(h1g + ((u64)2*512 + rowbase + pr)*32 + pu,
                               __ATOMIC_RELAXED, __HIP_MEMORY_SCOPE_AGENT);
    __syncthreads();

    float hv[4] = {0.f,0.f,0.f,0.f};
    for(int t = 0; t < 512; t++){
      const int cur = t & 1, nxt = cur ^ 1;

      bf8 B[8];
      const u16* br2 = &h2b[cur][l15][quad*8];
#pragma unroll
      for(int kt = 0; kt < 4; kt++) B[kt] = *(const bf8*)(br2 + kt*32);
      const u16* br1 = &ring[t & 3][l15][quad*8];
#pragma unroll
      for(int kt = 0; kt < 4; kt++) B[4+kt] = *(const bf8*)(br1 + kt*32);

      // poll only if cached progress insufficient; prefetch h1(t+3)
      u64 pnew = 0;
      if(t < 509){
        const int need = t + 4;
        while(seen < need){
          seen = __hip_atomic_load(prog + rb, __ATOMIC_ACQUIRE, __HIP_MEMORY_SCOPE_AGENT);
          if(seen < need) __builtin_amdgcn_s_sleep(2);
        }
        pnew = __hip_atomic_load(h1g + ((u64)(t+3)*512 + rowbase + pr)*32 + pu,
                                 __ATOMIC_RELAXED, __HIP_MEMORY_SCOPE_AGENT);
      }

      f4 acc[4];
#pragma unroll
      for(int q = 0; q < 4; q++) acc[q] = bini[q];
#pragma unroll
      for(int kt = 0; kt < 8; kt++){
#pragma unroll
        for(int q = 0; q < 4; q++)
          acc[q] = __builtin_amdgcn_mfma_f32_16x16x32_bf16(A[q][kt], B[kt], acc[q], 0,0,0);
      }

      // stage h1(t+2) (loaded last step) into its ring slot
      if(t < 510) *(u64*)(&ring[(t+2) & 3][pr][pu*4]) = pv;

      u64 hpack; u16* hp = (u16*)&hpack;
#pragma unroll
      for(int r = 0; r < 4; r++){
        float ig = sigm_ps(acc[0][r]);
        float fg = sigm_ps(acc[1][r]);
        float gg = 2.f*sigm_ps(acc[2][r]) - 1.f;
        float og = sigm_ps(acc[3][r]);
        c[r] = fg*c[r] + ig*gg;
        float th = 2.f*sigm_ps(c[r]*(2.f*LOG2E)) - 1.f;
        hv[r] = og*th;
        hp[r] = f2bf(hv[r]);
      }
      *(u64*)(&h2b[nxt][l15][16*wave + quad*4]) = hpack;

      // lgkm-only barrier (no stores in flight need draining)
      __builtin_amdgcn_sched_barrier(0);
      asm volatile("s_waitcnt lgkmcnt(0)" ::: "memory");
      __builtin_amdgcn_s_barrier();
      __builtin_amdgcn_sched_barrier(0);

      pv = pnew;
    }
    // stash final h2 (f32) for FC head
#pragma unroll
    for(int r = 0; r < 4; r++) ffin[l15][16*wave + quad*4 + r] = hv[r];
    __syncthreads();

    // ---- FC head: per row r, 64 hidden, 32 threads x 2v each
    {
      int r = tid >> 5, u = tid & 31;
      float s0 = bfc1[2*u], s1 = bfc1[2*u+1];
      const float* w0 = Wfc1 + (2*u)*128;
      const float* w1 = Wfc1 + (2*u+1)*128;
      for(int j = 0; j < 128; j++){
        float h = ffin[r][j];
        s0 = fmaf(w0[j], h, s0);
        s1 = fmaf(w1[j], h, s1);
      }
      float term = fmaxf(s0, 0.f)*Wfc2[2*u] + fmaxf(s1, 0.f)*Wfc2[2*u+1];
#pragma unroll
      for(int off = 16; off > 0; off >>= 1) term += __shfl_down(term, off, 32);
      if(u == 0) out[rowbase + r] = sigm_ps((term + bfc2[0]) * LOG2E);
    }
  }
}

// ---------------------------------------------------------------------------
extern "C" void kernel_launch(void* const* d_in, const int* in_sizes, int n_in,
                              void* d_out, int out_size, void* d_ws, size_t ws_size,
                              hipStream_t stream){
  const float* x    = (const float*)d_in[0];
  const float* Wih0 = (const float*)d_in[1];
  const float* Whh0 = (const float*)d_in[2];
  const float* bih0 = (const float*)d_in[3];
  const float* bhh0 = (const float*)d_in[4];
  const float* Wih1 = (const float*)d_in[5];
  const float* Whh1 = (const float*)d_in[6];
  const float* bih1 = (const float*)d_in[7];
  const float* bhh1 = (const float*)d_in[8];
  const float* Wfc1 = (const float*)d_in[9];
  const float* bfc1 = (const float*)d_in[10];
  const float* Wfc2 = (const float*)d_in[11];
  const float* bfc2 = (const float*)d_in[12];

  char* ws = (char*)d_ws;
  u16*   W0c   = (u16*)(ws);                       // 512*160*2 = 163840 B
  u16*   W1c   = (u16*)(ws + 163840);              // 512*256*2 = 262144 B
  float* bias0 = (float*)(ws + 163840 + 262144);   // 2048 B
  float* bias1 = bias0 + 512;                      // 2048 B
  int*   prog  = (int*)(ws + 163840 + 262144 + 4096);  // 128 B (pad to 256)
  u64*   h1g   = (u64*)(ws + 163840 + 262144 + 4096 + 256); // 64 MiB

  prep_kernel<<<dim3(512), dim3(64), 0, stream>>>(Wih0, Whh0, bih0, bhh0,
                                                  Wih1, Whh1, bih1, bhh1,
                                                  W0c, W1c, bias0, bias1, prog);

  lstm_fused<<<dim3(64), dim3(512), 0, stream>>>(
      W0c, W1c, bias0, bias1, x, h1g, prog,
      Wfc1, bfc1, Wfc2, bfc2, (float*)d_out);
}

// Round 2
// 635.942 us; speedup vs baseline: 1.3399x; 1.3399x over previous
//
#include <hip/hip_runtime.h>
#include <stdint.h>

typedef short bf8 __attribute__((ext_vector_type(8)));   // 8 bf16 (4 VGPRs)
typedef float f4  __attribute__((ext_vector_type(4)));   // MFMA acc
typedef unsigned short u16;
typedef unsigned long long u64;

#define LOG2E 1.4426950408889634f

__device__ __forceinline__ u16 f2bf(float f){
  uint32_t u = __builtin_bit_cast(uint32_t, f);
  u += 0x7fffu + ((u >> 16) & 1u);
  return (u16)(u >> 16);
}

// Fused LSTM cell from prescaled pre-activations.
// ai,af,ao prescaled by log2e; ag by 2*log2e; E* = 2^-a*.
// c' = c/(1+Ef) + (1-Eg)/((1+Ei)(1+Eg))   [one rcp via common denominator]
// h  = (1-Ec)/((1+Eo)(1+Ec)),  Ec = 2^(-2*log2e*c')
// 5 exp2 + 2 rcp = 7 trans ops (was 10).
__device__ __forceinline__ float lstm_cell(float ai, float af, float ag, float ao, float& c){
  float Ei = __builtin_amdgcn_exp2f(-ai);
  float Ef = __builtin_amdgcn_exp2f(-af);
  float Eg = __builtin_amdgcn_exp2f(-ag);
  float Eo = __builtin_amdgcn_exp2f(-ao);
  float m1  = (1.f + Ei) * (1.f + Eg);
  float a3  = 1.f + Ef;
  float num = fmaf(c, m1, (1.f - Eg) * a3);
  c = num * __builtin_amdgcn_rcpf(a3 * m1);
  float Ec = __builtin_amdgcn_exp2f(c * (-2.f * LOG2E));
  return (1.f - Ec) * __builtin_amdgcn_rcpf((1.f + Eo) * (1.f + Ec));
}

// ---------------------------------------------------------------------------
// Prep: prescaled bf16 weights W0c[512][160]=[Whh0|Wih0|0], W1c[512][256]=
// [Whh1|Wih1]; rows scaled log2e (i,f,o) / 2*log2e (g); prescaled biases;
// zero the progress counters (ws is poisoned 0xAA before every launch!).
// ---------------------------------------------------------------------------
__global__ void prep_kernel(const float* __restrict__ Wih0, const float* __restrict__ Whh0,
                            const float* __restrict__ bih0, const float* __restrict__ bhh0,
                            const float* __restrict__ Wih1, const float* __restrict__ Whh1,
                            const float* __restrict__ bih1, const float* __restrict__ bhh1,
                            u16* __restrict__ W0c, u16* __restrict__ W1c,
                            float* __restrict__ bias0, float* __restrict__ bias1,
                            int* __restrict__ prog){
  int g = blockIdx.x;      // gate row 0..511
  int t = threadIdx.x;     // 0..63
  float s = (g >= 256 && g < 384) ? 2.0f * LOG2E : LOG2E;
  for(int k = t; k < 160; k += 64){
    float v = 0.0f;
    if(k < 128)      v = Whh0[g*128 + k];
    else if(k < 146) v = Wih0[g*18 + (k-128)];
    W0c[g*160 + k] = f2bf(v * s);
  }
  for(int k = t; k < 256; k += 64){
    float v = (k < 128) ? Whh1[g*128 + k] : Wih1[g*128 + (k-128)];
    W1c[g*256 + k] = f2bf(v * s);
  }
  if(t == 0){
    bias0[g] = (bih0[g] + bhh0[g]) * s;
    bias1[g] = (bih1[g] + bhh1[g]) * s;
  }
  if(g == 0 && t < 32) prog[t] = 0;
}

// ---------------------------------------------------------------------------
// Fused 2-layer LSTM. 64 blocks x 512 threads; bid<32: L0 role, else L1.
// KEY fixes this round:
//  * __launch_bounds__(512,1): 256-VGPR budget so the 128-VGPR weight frags
//    (L1: A2[4][4]+A1[4][4]) stay RESIDENT (with (512,2) they were reloaded
//    from memory every step -> the old 3840-cyc step floor).
//  * Dependent-chain halving: the h1 operand (L1) / x operand (L0) is known
//    a step ahead -> precompute pre[q] = bias + (that part) off-chain; the
//    per-step chain is barrier -> ds_read h -> 4 MFMA -> cell -> write.
//  * 7-trans cell update (common-denominator sigmoids).
// ---------------------------------------------------------------------------
__global__ __launch_bounds__(512, 1)
void lstm_fused(const u16* __restrict__ Wc0, const u16* __restrict__ Wc1,
                const float* __restrict__ bias0, const float* __restrict__ bias1,
                const float* __restrict__ xin,   // (512,512,18) f32
                u64* __restrict__ h1g,           // [T][512 rows][32 u64] bf16x4
                int* __restrict__ prog,          // [32] per-rowblock progress
                const float* __restrict__ Wfc1, const float* __restrict__ bfc1,
                const float* __restrict__ Wfc2, const float* __restrict__ bfc2,
                float* __restrict__ out)         // (512,) f32
{
  __shared__ __align__(16) u16  hb[2][16][136];   // L0 h-state (cols 0..127)
  __shared__ __align__(16) u16  xb[2][16][40];    // L0 x tiles (cols 18..31 stay 0)
  __shared__ __align__(16) u16  h2b[2][16][136];  // L1 h2 state
  __shared__ __align__(16) u16  ring[4][16][136]; // L1 h1 ring (slot read at step s-1 for pre)
  __shared__ __align__(16) float ffin[16][132];   // final h2 f32 for FC head

  const int tid  = threadIdx.x;
  const int wave = tid >> 6;
  const int lane = tid & 63;
  const int quad = lane >> 4;
  const int l15  = lane & 15;
  const bool isL0 = (blockIdx.x < 32);
  const int rb   = isL0 ? blockIdx.x : (blockIdx.x - 32);
  const int rowbase = rb * 16;

  if(isL0){
    // ------------- L0: h-part K=128 (kt0..3) + x-part K=32 (own tile) -----
    bf8 Ah[4][4], Ax[4];
#pragma unroll
    for(int q = 0; q < 4; q++){
      const u16* wp = Wc0 + (u64)(128*q + 16*wave + l15)*160 + quad*8;
#pragma unroll
      for(int kt = 0; kt < 4; kt++) Ah[q][kt] = *(const bf8*)(wp + kt*32);
      Ax[q] = *(const bf8*)(wp + 128);
    }
    f4 bini[4];
#pragma unroll
    for(int q = 0; q < 4; q++) bini[q] = *(const f4*)(bias0 + 128*q + 16*wave + quad*4);
    float c[4] = {0.f,0.f,0.f,0.f};

    for(int i = tid; i < 2*16*136; i += 512) ((u16*)hb)[i] = 0;
    for(int i = tid; i < 2*16*40;  i += 512) ((u16*)xb)[i] = 0;
    __syncthreads();

    int sr = 0, sk = 0;
    if(tid < 288){
      sr = tid/18; sk = tid - 18*sr;
      xb[0][sr][sk] = f2bf(xin[((u64)(rowbase+sr)*512 + 0)*18 + sk]);
      xb[1][sr][sk] = f2bf(xin[((u64)(rowbase+sr)*512 + 1)*18 + sk]);
    }
    float xv = 0.f;
    if(tid < 288) xv = xin[((u64)(rowbase+sr)*512 + 2)*18 + sk];
    __syncthreads();

    f4 pre[4];
    {
      bf8 Bx = *(const bf8*)(&xb[0][l15][quad*8]);
#pragma unroll
      for(int q = 0; q < 4; q++)
        pre[q] = __builtin_amdgcn_mfma_f32_16x16x32_bf16(Ax[q], Bx, bini[q], 0,0,0);
    }
    __syncthreads();   // xb[0] gets overwritten at t=0

    for(int t = 0; t < 512; t++){
      const int cur = t & 1, nxt = cur ^ 1;
      // stage x(t+2) from reg; issue load of x(t+3) (uniform vmem count)
      if(tid < 288){
        if(t <= 509) xb[t & 1][sr][sk] = f2bf(xv);
        const int tl = (t + 3 < 512) ? t + 3 : 511;
        xv = xin[((u64)(rowbase+sr)*512 + tl)*18 + sk];
      }

      bf8 B[4];
      const u16* br = &hb[cur][l15][quad*8];
#pragma unroll
      for(int kt = 0; kt < 4; kt++) B[kt] = *(const bf8*)(br + kt*32);

      f4 acc[4];
#pragma unroll
      for(int q = 0; q < 4; q++){
        f4 a = pre[q];
#pragma unroll
        for(int kt = 0; kt < 4; kt++)
          a = __builtin_amdgcn_mfma_f32_16x16x32_bf16(Ah[q][kt], B[kt], a, 0,0,0);
        acc[q] = a;
      }

      u64 hpack; u16* hp = (u16*)&hpack;
#pragma unroll
      for(int r = 0; r < 4; r++)
        hp[r] = f2bf(lstm_cell(acc[0][r], acc[1][r], acc[2][r], acc[3][r], c[r]));

      *(u64*)(&hb[nxt][l15][16*wave + quad*4]) = hpack;
      __hip_atomic_store(h1g + ((u64)t*512 + rowbase + l15)*32 + 4*wave + quad,
                         hpack, __ATOMIC_RELAXED, __HIP_MEMORY_SCOPE_AGENT);

      // precompute x-part for step t+1 (off the dependent chain)
      if(t < 511){
        bf8 Bx = *(const bf8*)(&xb[(t+1) & 1][l15][quad*8]);
#pragma unroll
        for(int q = 0; q < 4; q++)
          pre[q] = __builtin_amdgcn_mfma_f32_16x16x32_bf16(Ax[q], Bx, bini[q], 0,0,0);
      }

      // counted-vmcnt barrier. Per step, waves 0-4 issue [xload, h1store],
      // waves 5-7 [h1store]. vmcnt(4)/(2) ==> store(t-2) retired (in-order),
      // so publishing prog = t-1 is completion-safe with a relaxed store.
      __builtin_amdgcn_sched_barrier(0);
      if(wave < 5) asm volatile("s_waitcnt vmcnt(4) lgkmcnt(0)" ::: "memory");
      else         asm volatile("s_waitcnt vmcnt(2) lgkmcnt(0)" ::: "memory");
      __builtin_amdgcn_s_barrier();
      __builtin_amdgcn_sched_barrier(0);
      if(tid == 0 && t > 0)
        __hip_atomic_store(prog + rb, t - 1, __ATOMIC_RELAXED, __HIP_MEMORY_SCOPE_AGENT);
    }
    asm volatile("s_waitcnt vmcnt(0)" ::: "memory");
    __builtin_amdgcn_s_barrier();
    if(tid == 0)
      __hip_atomic_store(prog + rb, 512, __ATOMIC_RELAXED, __HIP_MEMORY_SCOPE_AGENT);
  } else {
    // ------------- L1: h2-part K=128 (chain) + h1-part K=128 (pre) --------
    bf8 A2[4][4], A1[4][4];
#pragma unroll
    for(int q = 0; q < 4; q++){
      const u16* wp = Wc1 + (u64)(128*q + 16*wave + l15)*256 + quad*8;
#pragma unroll
      for(int kt = 0; kt < 4; kt++){
        A2[q][kt] = *(const bf8*)(wp + kt*32);
        A1[q][kt] = *(const bf8*)(wp + 128 + kt*32);
      }
    }
    f4 bini[4];
#pragma unroll
    for(int q = 0; q < 4; q++) bini[q] = *(const f4*)(bias1 + 128*q + 16*wave + quad*4);
    float c[4] = {0.f,0.f,0.f,0.f};

    for(int i = tid; i < 2*16*136; i += 512) ((u16*)h2b)[i] = 0;

    const int pr = tid >> 5;          // staging row 0..15
    const int pu = tid & 31;          // staging u64-chunk (4 comps)
    int seen = 0;
    __syncthreads();

    // prologue: stage h1(0)->ring0, h1(1)->ring1; preload pv=h1(2)
    while(seen < 2){
      seen = __hip_atomic_load(prog + rb, __ATOMIC_ACQUIRE, __HIP_MEMORY_SCOPE_AGENT);
      if(seen < 2) __builtin_amdgcn_s_sleep(2);
    }
    {
      u64 v0 = __hip_atomic_load(h1g + ((u64)0*512 + rowbase + pr)*32 + pu,
                                 __ATOMIC_RELAXED, __HIP_MEMORY_SCOPE_AGENT);
      *(u64*)(&ring[0][pr][pu*4]) = v0;
      u64 v1 = __hip_atomic_load(h1g + ((u64)1*512 + rowbase + pr)*32 + pu,
                                 __ATOMIC_RELAXED, __HIP_MEMORY_SCOPE_AGENT);
      *(u64*)(&ring[1][pr][pu*4]) = v1;
    }
    while(seen < 3){
      seen = __hip_atomic_load(prog + rb, __ATOMIC_ACQUIRE, __HIP_MEMORY_SCOPE_AGENT);
      if(seen < 3) __builtin_amdgcn_s_sleep(2);
    }
    u64 pv = __hip_atomic_load(h1g + ((u64)2*512 + rowbase + pr)*32 + pu,
                               __ATOMIC_RELAXED, __HIP_MEMORY_SCOPE_AGENT);
    __syncthreads();

    f4 pre[4];
    {
      const u16* rr = &ring[0][l15][quad*8];
#pragma unroll
      for(int q = 0; q < 4; q++){
        f4 a = bini[q];
#pragma unroll
        for(int kt = 0; kt < 4; kt++)
          a = __builtin_amdgcn_mfma_f32_16x16x32_bf16(A1[q][kt], *(const bf8*)(rr + kt*32), a, 0,0,0);
        pre[q] = a;
      }
    }

    float hv[4] = {0.f,0.f,0.f,0.f};
    for(int t = 0; t < 512; t++){
      const int cur = t & 1, nxt = cur ^ 1;

      bf8 B2[4];
      const u16* br2 = &h2b[cur][l15][quad*8];
#pragma unroll
      for(int kt = 0; kt < 4; kt++) B2[kt] = *(const bf8*)(br2 + kt*32);

      // amortized poll + prefetch h1(t+3)
      u64 pnew = 0;
      if(t <= 508){
        const int need = t + 4;
        while(seen < need){
          seen = __hip_atomic_load(prog + rb, __ATOMIC_ACQUIRE, __HIP_MEMORY_SCOPE_AGENT);
          if(seen < need) __builtin_amdgcn_s_sleep(2);
        }
        pnew = __hip_atomic_load(h1g + ((u64)(t+3)*512 + rowbase + pr)*32 + pu,
                                 __ATOMIC_RELAXED, __HIP_MEMORY_SCOPE_AGENT);
      }

      // 4-deep chain seeded with pre (h1(t) contribution + bias)
      f4 acc[4];
#pragma unroll
      for(int q = 0; q < 4; q++){
        f4 a = pre[q];
#pragma unroll
        for(int kt = 0; kt < 4; kt++)
          a = __builtin_amdgcn_mfma_f32_16x16x32_bf16(A2[q][kt], B2[kt], a, 0,0,0);
        acc[q] = a;
      }

      // precompute h1(t+1) contribution for next step (off-chain)
      if(t < 511){
        const u16* rr = &ring[(t+1) & 3][l15][quad*8];
#pragma unroll
        for(int q = 0; q < 4; q++){
          f4 a = bini[q];
#pragma unroll
          for(int kt = 0; kt < 4; kt++)
            a = __builtin_amdgcn_mfma_f32_16x16x32_bf16(A1[q][kt], *(const bf8*)(rr + kt*32), a, 0,0,0);
          pre[q] = a;
        }
      }

      // stage h1(t+2) (loaded last step) into its ring slot
      if(t <= 509) *(u64*)(&ring[(t+2) & 3][pr][pu*4]) = pv;

      u64 hpack; u16* hp = (u16*)&hpack;
#pragma unroll
      for(int r = 0; r < 4; r++){
        hv[r] = lstm_cell(acc[0][r], acc[1][r], acc[2][r], acc[3][r], c[r]);
        hp[r] = f2bf(hv[r]);
      }
      *(u64*)(&h2b[nxt][l15][16*wave + quad*4]) = hpack;

      __builtin_amdgcn_sched_barrier(0);
      asm volatile("s_waitcnt lgkmcnt(0)" ::: "memory");
      __builtin_amdgcn_s_barrier();
      __builtin_amdgcn_sched_barrier(0);

      pv = pnew;
    }
    // stash final h2 (f32) for FC head
#pragma unroll
    for(int r = 0; r < 4; r++) ffin[l15][16*wave + quad*4 + r] = hv[r];
    __syncthreads();

    // ---- FC head: per row r, 64 hidden, 32 threads x 2v each
    {
      int r = tid >> 5, u = tid & 31;
      float s0 = bfc1[2*u], s1 = bfc1[2*u+1];
      const float* w0 = Wfc1 + (2*u)*128;
      const float* w1 = Wfc1 + (2*u+1)*128;
      for(int j = 0; j < 128; j++){
        float h = ffin[r][j];
        s0 = fmaf(w0[j], h, s0);
        s1 = fmaf(w1[j], h, s1);
      }
      float term = fmaxf(s0, 0.f)*Wfc2[2*u] + fmaxf(s1, 0.f)*Wfc2[2*u+1];
#pragma unroll
      for(int off = 16; off > 0; off >>= 1) term += __shfl_down(term, off, 32);
      if(u == 0){
        float z = (term + bfc2[0]) * LOG2E;
        out[rowbase + r] = __builtin_amdgcn_rcpf(1.0f + __builtin_amdgcn_exp2f(-z));
      }
    }
  }
}

// ---------------------------------------------------------------------------
extern "C" void kernel_launch(void* const* d_in, const int* in_sizes, int n_in,
                              void* d_out, int out_size, void* d_ws, size_t ws_size,
                              hipStream_t stream){
  const float* x    = (const float*)d_in[0];
  const float* Wih0 = (const float*)d_in[1];
  const float* Whh0 = (const float*)d_in[2];
  const float* bih0 = (const float*)d_in[3];
  const float* bhh0 = (const float*)d_in[4];
  const float* Wih1 = (const float*)d_in[5];
  const float* Whh1 = (const float*)d_in[6];
  const float* bih1 = (const float*)d_in[7];
  const float* bhh1 = (const float*)d_in[8];
  const float* Wfc1 = (const float*)d_in[9];
  const float* bfc1 = (const float*)d_in[10];
  const float* Wfc2 = (const float*)d_in[11];
  const float* bfc2 = (const float*)d_in[12];

  char* ws = (char*)d_ws;
  u16*   W0c   = (u16*)(ws);                       // 512*160*2 = 163840 B
  u16*   W1c   = (u16*)(ws + 163840);              // 512*256*2 = 262144 B
  float* bias0 = (float*)(ws + 163840 + 262144);   // 2048 B
  float* bias1 = bias0 + 512;                      // 2048 B
  int*   prog  = (int*)(ws + 163840 + 262144 + 4096);  // 128 B (pad to 256)
  u64*   h1g   = (u64*)(ws + 163840 + 262144 + 4096 + 256); // 64 MiB

  prep_kernel<<<dim3(512), dim3(64), 0, stream>>>(Wih0, Whh0, bih0, bhh0,
                                                  Wih1, Whh1, bih1, bhh1,
                                                  W0c, W1c, bias0, bias1, prog);

  lstm_fused<<<dim3(64), dim3(512), 0, stream>>>(
      W0c, W1c, bias0, bias1, x, h1g, prog,
      Wfc1, bfc1, Wfc2, bfc2, (float*)d_out);
}